// Round 8
// baseline (1660.357 us; speedup 1.0000x reference)
//
#include <hip/hip_runtime.h>

#define N_NODES 200000
#define N_DIM   64
#define N_EDGES 6400000
#define NBK     3125            // buckets of 64 rows
#define NSB     250             // sort blocks
#define EPB     (N_EDGES/NSB)   // 25600 edges per sort block
#define ROWSORT_CAP 4096        // LDS-staged bucket cap (avg 2048, +45 sigma)
#define T_TILES 16              // column tiles
#define TILE_DIV 12500          // cols per tile (200000/16): 3.2 MB of x per tile < 4 MB L2
#define RPB 208                 // rows per spmm block (16 groups x 13 rows)
#define RPG 13                  // rows per 16-lane group
#define SPMM_BLOCKS ((N_NODES + RPB - 1) / RPB)   // 962 -> fully resident grid

// ---- P1: per-sort-block histogram over 3125 buckets (LDS atomics only) ----
__global__ __launch_bounds__(256) void k_hist(const int* __restrict__ rows,
                                              int* __restrict__ mat) {
    __shared__ int h[NBK];
    int t = threadIdx.x;
    for (int i = t; i < NBK; i += 256) h[i] = 0;
    __syncthreads();
    int start = blockIdx.x * EPB;
    for (int j = t; j < EPB; j += 256) {
        int r = rows[start + j];
        atomicAdd(&h[r >> 6], 1);
    }
    __syncthreads();
    int* m = mat + blockIdx.x * NBK;
    for (int i = t; i < NBK; i += 256) m[i] = h[i];
}

// ---- P2a: per-bucket totals ----
__global__ __launch_bounds__(256) void k_tot(const int* __restrict__ mat,
                                             int* __restrict__ tot) {
    int b = blockIdx.x * 256 + threadIdx.x;
    if (b >= NBK) return;
    int s = 0;
    for (int blk = 0; blk < NSB; ++blk) s += mat[blk * NBK + b];
    tot[b] = s;
}

// ---- P2b: exclusive scan of 3125 totals -> base[], base[NBK]=E ----
__global__ __launch_bounds__(256) void k_scanbase(const int* __restrict__ tot,
                                                  int* __restrict__ base) {
    __shared__ int sm[256];
    int t = threadIdx.x;
    const int C = 13;                       // 256*13 = 3328 >= 3125
    int c0 = t * C;
    int loc[C];
    int s = 0;
#pragma unroll
    for (int i = 0; i < C; ++i) {
        int b = c0 + i;
        loc[i] = (b < NBK) ? tot[b] : 0;
        s += loc[i];
    }
    sm[t] = s;
    __syncthreads();
    for (int off = 1; off < 256; off <<= 1) {
        int x = (t >= off) ? sm[t - off] : 0;
        __syncthreads();
        sm[t] += x;
        __syncthreads();
    }
    int run = (t == 0) ? 0 : sm[t - 1];
#pragma unroll
    for (int i = 0; i < C; ++i) {
        int b = c0 + i;
        if (b < NBK) base[b] = run;
        run += loc[i];
    }
    if (t == 255) base[NBK] = run;          // = E
}

// ---- P2c: rebase mat[blk][b] to global write positions ----
__global__ __launch_bounds__(256) void k_rebase(int* __restrict__ mat,
                                                const int* __restrict__ base) {
    int b = blockIdx.x * 256 + threadIdx.x;
    if (b >= NBK) return;
    int run = base[b];
    for (int blk = 0; blk < NSB; ++blk) {
        int v = mat[blk * NBK + b];
        mat[blk * NBK + b] = run;
        run += v;
    }
}

// ---- P3: scatter edges into bucket-sorted slots (LDS cursors) ----
__global__ __launch_bounds__(256) void k_scatter(const int* __restrict__ rows,
                                                 const int* __restrict__ cols,
                                                 const float* __restrict__ vals,
                                                 const int* __restrict__ mat,
                                                 int2* __restrict__ slots) {
    __shared__ int cur[NBK];
    int t = threadIdx.x;
    const int* m = mat + blockIdx.x * NBK;
    for (int i = t; i < NBK; i += 256) cur[i] = m[i];
    __syncthreads();
    int start = blockIdx.x * EPB;
    for (int j = t; j < EPB; j += 256) {
        int e = start + j;
        int r = rows[e];
        int pos = atomicAdd(&cur[r >> 6], 1);
        slots[pos] = make_int2(((r & 63) << 18) | cols[e], __float_as_int(vals[e]));
    }
}

// ---- P4: in-bucket counting sort by (row, col-tile); emit rowoff + per-(row,tile) counts ----
__global__ __launch_bounds__(256) void k_rowsort(const int* __restrict__ base,
                                                 int2* __restrict__ slots,
                                                 int2* __restrict__ spill,
                                                 int* __restrict__ rowoff,
                                                 unsigned char* __restrict__ cnt8) {
    __shared__ int2 buf[ROWSORT_CAP];       // 32 KiB
    __shared__ int cnt2[1024], pos2[1024], cur2[1024];
    __shared__ int sm[256];
    int t = threadIdx.x, b = blockIdx.x;
    int s0 = base[b], s1 = base[b + 1], n = s1 - s0;
    for (int i = t; i < 1024; i += 256) cnt2[i] = 0;
    __syncthreads();
    bool lds = (n <= ROWSORT_CAP);
    if (lds) {
        for (int i = t; i < n; i += 256) {
            int2 v = slots[s0 + i];
            buf[i] = v;
            int col = v.x & 0x3FFFF;
            int key = ((((unsigned)v.x) >> 18) << 4) | (unsigned)(col / TILE_DIV);
            atomicAdd(&cnt2[key], 1);
        }
    } else {                                // statistically unreachable fallback
        for (int i = t; i < n; i += 256) {
            int2 v = slots[s0 + i];
            spill[s0 + i] = v;
            int col = v.x & 0x3FFFF;
            int key = ((((unsigned)v.x) >> 18) << 4) | (unsigned)(col / TILE_DIV);
            atomicAdd(&cnt2[key], 1);
        }
        __threadfence();
    }
    __syncthreads();
    // exclusive scan of 1024 counts: 4 per thread + block scan
    int b4 = t << 2;
    int l0 = cnt2[b4], l1 = cnt2[b4 + 1], l2 = cnt2[b4 + 2], l3 = cnt2[b4 + 3];
    sm[t] = l0 + l1 + l2 + l3;
    __syncthreads();
    for (int off = 1; off < 256; off <<= 1) {
        int xv = (t >= off) ? sm[t - off] : 0;
        __syncthreads();
        sm[t] += xv;
        __syncthreads();
    }
    int run = (t == 0) ? 0 : sm[t - 1];
    pos2[b4] = run;           cur2[b4] = run;
    pos2[b4 + 1] = run + l0;  cur2[b4 + 1] = run + l0;
    pos2[b4 + 2] = run + l0 + l1;       cur2[b4 + 2] = run + l0 + l1;
    pos2[b4 + 3] = run + l0 + l1 + l2;  cur2[b4 + 3] = run + l0 + l1 + l2;
    __syncthreads();
    // emit per-row start + per-(row,tile) counts
    if (t < 64) {
        int gr = (b << 6) + t;
        rowoff[gr] = s0 + pos2[t << 4];
#pragma unroll
        for (int tt = 0; tt < T_TILES; ++tt)
            cnt8[tt * N_NODES + gr] = (unsigned char)cnt2[(t << 4) + tt];
    }
    __syncthreads();
    // scatter into (row,tile)-sorted order, clearing the row tag
    if (lds) {
        for (int i = t; i < n; i += 256) {
            int2 v = buf[i];
            int col = v.x & 0x3FFFF;
            int key = ((((unsigned)v.x) >> 18) << 4) | (unsigned)(col / TILE_DIV);
            int p = atomicAdd(&cur2[key], 1);
            slots[s0 + p] = make_int2(col, v.y);
        }
    } else {
        for (int i = t; i < n; i += 256) {
            int2 v = spill[s0 + i];
            int col = v.x & 0x3FFFF;
            int key = ((((unsigned)v.x) >> 18) << 4) | (unsigned)(col / TILE_DIV);
            int p = atomicAdd(&cur2[key], 1);
            slots[s0 + p] = make_int2(col, v.y);
        }
    }
}

// ---- SpMM: tile-lockstep, fully-resident grid, register accumulators ----
// 16 lanes per row-dim-slice; each group owns 13 rows with persistent cursors.
// MODE 0: h=A@x; y=h; out = emb + h
// MODE 1: h=A@x; y=h; out += h
// MODE 2: h=A@x;      out = (out + h) * 0.25
template <int MODE>
__global__ __launch_bounds__(256) void spmm(const int* __restrict__ rowoff,
                                            const unsigned char* __restrict__ cnt8,
                                            const long long* __restrict__ slots,
                                            const float* __restrict__ x,
                                            float* __restrict__ y,
                                            const float* __restrict__ emb,
                                            float* __restrict__ out) {
    int t    = threadIdx.x;
    int g    = t >> 4;
    int lane = t & 15;
    int r0   = blockIdx.x * RPB + g * RPG;

    float4 acc[RPG];
    int cur[RPG];
#pragma unroll
    for (int i = 0; i < RPG; ++i) {
        acc[i] = make_float4(0.f, 0.f, 0.f, 0.f);
        int r = r0 + i;
        cur[i] = (r < N_NODES) ? rowoff[r] : 0;
    }

    for (int tt = 0; tt < T_TILES; ++tt) {
        const unsigned char* cp = cnt8 + tt * N_NODES;
#pragma unroll
        for (int i = 0; i < RPG; ++i) {
            int r = r0 + i;
            if (r < N_NODES) {
                int c  = cp[r];
                int j  = cur[i], je = j + c;
                cur[i] = je;
                for (; j + 2 <= je; j += 2) {
                    unsigned long long e0 = *(const unsigned long long*)&slots[j];
                    unsigned long long e1 = *(const unsigned long long*)&slots[j + 1];
                    const float4 x0 = *reinterpret_cast<const float4*>(
                        x + (((int)(e0 & 0x3FFFFu)) << 6) + (lane << 2));
                    const float4 x1 = *reinterpret_cast<const float4*>(
                        x + (((int)(e1 & 0x3FFFFu)) << 6) + (lane << 2));
                    float v0 = __int_as_float((int)(e0 >> 32));
                    float v1 = __int_as_float((int)(e1 >> 32));
                    acc[i].x = fmaf(v0, x0.x, acc[i].x);
                    acc[i].y = fmaf(v0, x0.y, acc[i].y);
                    acc[i].z = fmaf(v0, x0.z, acc[i].z);
                    acc[i].w = fmaf(v0, x0.w, acc[i].w);
                    acc[i].x = fmaf(v1, x1.x, acc[i].x);
                    acc[i].y = fmaf(v1, x1.y, acc[i].y);
                    acc[i].z = fmaf(v1, x1.z, acc[i].z);
                    acc[i].w = fmaf(v1, x1.w, acc[i].w);
                }
                if (j < je) {
                    unsigned long long e0 = *(const unsigned long long*)&slots[j];
                    const float4 x0 = *reinterpret_cast<const float4*>(
                        x + (((int)(e0 & 0x3FFFFu)) << 6) + (lane << 2));
                    float v0 = __int_as_float((int)(e0 >> 32));
                    acc[i].x = fmaf(v0, x0.x, acc[i].x);
                    acc[i].y = fmaf(v0, x0.y, acc[i].y);
                    acc[i].z = fmaf(v0, x0.z, acc[i].z);
                    acc[i].w = fmaf(v0, x0.w, acc[i].w);
                }
            }
        }
    }

#pragma unroll
    for (int i = 0; i < RPG; ++i) {
        int r = r0 + i;
        if (r < N_NODES) {
            int o = (r << 6) + (lane << 2);
            if (MODE == 0) {
                float4 e = *reinterpret_cast<const float4*>(emb + o);
                *reinterpret_cast<float4*>(y + o) = acc[i];
                *reinterpret_cast<float4*>(out + o) =
                    make_float4(e.x + acc[i].x, e.y + acc[i].y,
                                e.z + acc[i].z, e.w + acc[i].w);
            } else if (MODE == 1) {
                float4 a = *reinterpret_cast<const float4*>(out + o);
                *reinterpret_cast<float4*>(y + o) = acc[i];
                *reinterpret_cast<float4*>(out + o) =
                    make_float4(a.x + acc[i].x, a.y + acc[i].y,
                                a.z + acc[i].z, a.w + acc[i].w);
            } else {
                float4 a = *reinterpret_cast<const float4*>(out + o);
                *reinterpret_cast<float4*>(out + o) =
                    make_float4((a.x + acc[i].x) * 0.25f, (a.y + acc[i].y) * 0.25f,
                                (a.z + acc[i].z) * 0.25f, (a.w + acc[i].w) * 0.25f);
            }
        }
    }
}

// ---- launch ----
extern "C" void kernel_launch(void* const* d_in, const int* in_sizes, int n_in,
                              void* d_out, int out_size, void* d_ws, size_t ws_size,
                              hipStream_t stream) {
    const float* emb  = (const float*)d_in[0];
    const float* vals = (const float*)d_in[1];
    const int*   rows = (const int*)d_in[2];
    const int*   cols = (const int*)d_in[3];
    float*       out  = (float*)d_out;
    char*        ws   = (char*)d_ws;

    // workspace layout, total 157,700,016 B <= 157,794,304 proven in R1
    const size_t OFF_SLOTS  = 0;            // 51,200,000
    const size_t OFF_CNT8   = 51200000;     //  3,200,000 (16 tiles x 200000 uchar)
    const size_t OFF_TOT    = 54400000;     //     50,000
    const size_t OFF_BASE   = 54450000;     //     50,016
    const size_t OFF_ROWOFF = 54500016;     //    800,000
    const size_t OFF_BUFA   = 55300016;     // 51,200,000 (mat aliases: dead before spmm)
    const size_t OFF_BUFB   = 106500016;    // 51,200,000 (rowsort spill aliases)

    int2*          slots  = (int2*)(ws + OFF_SLOTS);
    unsigned char* cnt8   = (unsigned char*)(ws + OFF_CNT8);
    int*           tot    = (int*)(ws + OFF_TOT);
    int*           base   = (int*)(ws + OFF_BASE);
    int*           rowoff = (int*)(ws + OFF_ROWOFF);
    float*         bufA   = (float*)(ws + OFF_BUFA);
    float*         bufB   = (float*)(ws + OFF_BUFB);
    int*           mat    = (int*)(ws + OFF_BUFA);   // alias: live only during build

    k_hist    <<<NSB, 256, 0, stream>>>(rows, mat);
    k_tot     <<<13,  256, 0, stream>>>(mat, tot);
    k_scanbase<<<1,   256, 0, stream>>>(tot, base);
    k_rebase  <<<13,  256, 0, stream>>>(mat, base);
    k_scatter <<<NSB, 256, 0, stream>>>(rows, cols, vals, mat, slots);
    k_rowsort <<<NBK, 256, 0, stream>>>(base, slots, (int2*)bufB, rowoff, cnt8);

    spmm<0><<<SPMM_BLOCKS, 256, 0, stream>>>(rowoff, cnt8, (const long long*)slots,
                                             emb,  bufA, emb, out);
    spmm<1><<<SPMM_BLOCKS, 256, 0, stream>>>(rowoff, cnt8, (const long long*)slots,
                                             bufA, bufB, nullptr, out);
    spmm<2><<<SPMM_BLOCKS, 256, 0, stream>>>(rowoff, cnt8, (const long long*)slots,
                                             bufB, nullptr, nullptr, out);
}